// Round 7
// baseline (185581.458 us; speedup 1.0000x reference)
//
#include <hip/hip_runtime.h>

#define TT 4096
typedef unsigned int uint;
typedef unsigned long long u64;
typedef float f2 __attribute__((ext_vector_type(2)));
typedef float f32x4 __attribute__((ext_vector_type(4)));

#define TAGM 31u  // 5-bit wrap tag in mantissa LSBs (rel err 2^-19)

__device__ __forceinline__ float sigm(float x) { return 1.f / (1.f + __expf(-x)); }
__device__ __forceinline__ float ftanh(float x) {
  x = fminf(fmaxf(x, -15.f), 15.f);
  const float e = __expf(-2.f * x);
  return (1.f - e) / (1.f + e);
}
__device__ __forceinline__ void lds_wave_fence() {
  asm volatile("s_waitcnt lgkmcnt(0)" ::: "memory");
  __builtin_amdgcn_sched_barrier(0);
}
__device__ __forceinline__ uint tagw(float v, uint tg) {
  return (__float_as_uint(v) & ~TAGM) | tg;
}

// Dual post: plain cached store (write-through L1 -> home-XCD L2) + agent
// relaxed atomic to the shadow ring (visible at the die-level coherence pt).
__device__ __forceinline__ void post_dual(float* lp, float* sp, float v, uint tg) {
  const uint b = tagw(v, tg);
  asm volatile("global_store_dword %0, %1, off" :: "v"(lp), "v"(b) : "memory");
  __hip_atomic_store((uint*)sp, b, __ATOMIC_RELAXED, __HIP_MEMORY_SCOPE_AGENT);
}

// Poll one unit (6 floats, stride-8 ring). LOCAL path: buffer_inv (drop stale
// L1 lines) + plain loads -> same-XCD L2. Bounded; sticky fallback to AGENT
// atomics on the shadow ring (r3-proven protocol). Tag-match => fresh.
__device__ __forceinline__ void poll6(const float* lp, const float* sp, uint tg,
                                      float out[6], int& mode) {
  uint b0, b1, b2, b3, b4, b5;
  if (mode == 0) {
    for (int i = 0; i < 3000; ++i) {
      if (i) __builtin_amdgcn_s_sleep(1);
      asm volatile("buffer_inv\n\ts_waitcnt vmcnt(0)" ::: "memory");
      f32x4 r0; f2 r1;
      asm volatile(
          "global_load_dwordx4 %0, %2, off\n\t"
          "global_load_dwordx2 %1, %2, off offset:16\n\t"
          "s_waitcnt vmcnt(0)"
          : "=&v"(r0), "=&v"(r1) : "v"(lp) : "memory");
      b0 = __float_as_uint(r0[0]); b1 = __float_as_uint(r0[1]);
      b2 = __float_as_uint(r0[2]); b3 = __float_as_uint(r0[3]);
      b4 = __float_as_uint(r1[0]); b5 = __float_as_uint(r1[1]);
      if ((((b0 ^ tg) | (b1 ^ tg) | (b2 ^ tg) |
            (b3 ^ tg) | (b4 ^ tg) | (b5 ^ tg)) & TAGM) == 0u) goto done;
    }
    mode = 1;  // sticky: this thread uses the shadow ring from now on
  }
  for (;;) {
    {
      const u64* q = (const u64*)sp;
      const u64 a0 = __hip_atomic_load(q + 0, __ATOMIC_RELAXED, __HIP_MEMORY_SCOPE_AGENT);
      const u64 a1 = __hip_atomic_load(q + 1, __ATOMIC_RELAXED, __HIP_MEMORY_SCOPE_AGENT);
      const u64 a2 = __hip_atomic_load(q + 2, __ATOMIC_RELAXED, __HIP_MEMORY_SCOPE_AGENT);
      b0 = (uint)a0; b1 = (uint)(a0 >> 32); b2 = (uint)a1;
      b3 = (uint)(a1 >> 32); b4 = (uint)a2; b5 = (uint)(a2 >> 32);
      if ((((b0 ^ tg) | (b1 ^ tg) | (b2 ^ tg) |
            (b3 ^ tg) | (b4 ^ tg) | (b5 ^ tg)) & TAGM) == 0u) break;
    }
    __builtin_amdgcn_s_sleep(1);
  }
done:
  out[0] = __uint_as_float(b0 & ~TAGM); out[1] = __uint_as_float(b1 & ~TAGM);
  out[2] = __uint_as_float(b2 & ~TAGM); out[3] = __uint_as_float(b3 & ~TAGM);
  out[4] = __uint_as_float(b4 & ~TAGM); out[5] = __uint_as_float(b5 & ~TAGM);
}

// acc += v[0..5] * w ; v is 16B-aligned (stride-8 unit row) -> b128 + b64.
__device__ __forceinline__ void fma6(const float* vp, float w, f2 acc[3]) {
  const f32x4 v0 = *(const f32x4*)(vp);
  const f2 v1 = *(const f2*)(vp + 4);
  f2 lo; lo[0] = v0[0]; lo[1] = v0[1];
  f2 hi; hi[0] = v0[2]; hi[1] = v0[3];
  acc[0] += lo * w; acc[1] += hi * w; acc[2] += v1 * w;
}

// ================= K1: LSTM layer 1 — 32 workers x 512 thr, 16 units each ===
// Workers = blocks with bid%8==0 (XCD-0 under round-robin; perf bet only).
__global__ __launch_bounds__(512, 2) void k_l1(
    const float* __restrict__ x, const float* __restrict__ Wi,
    const float* __restrict__ Wh, const float* __restrict__ bias,
    float* h1L, float* h1S, float* h2L, float* h2S, float* c1fin, float* seq1) {
  if (blockIdx.x & 7) return;
  const int slot = blockIdx.x >> 3;  // 0..31
  __shared__ float xl[2][128 * 8];
  __shared__ float hl[512 * 8];
  __shared__ float zred[2][8 * 520];
  __shared__ float bs[64];
  const int tid = threadIdx.x;
  const int c = tid & 63, w = tid >> 6;
  const int u0 = slot * 16;
  const int gcol = ((c >> 4) * 512) + u0 + (c & 15);
  float wh[64], wx[16];
#pragma unroll
  for (int kk = 0; kk < 64; ++kk) wh[kk] = Wh[(size_t)(w * 64 + kk) * 2048 + gcol];
#pragma unroll
  for (int kk = 0; kk < 16; ++kk) wx[kk] = Wi[(size_t)(w * 16 + kk) * 2048 + gcol];
  if (tid < 64) bs[tid] = bias[((tid >> 4) * 512) + u0 + (tid & 15)];
  const int gj = tid / 6, gb = tid % 6;  // gate lanes: tid<96
  float creg = 0.f;
  int mode = 0;
  {  // stage x[0] (transpose [b][k] -> [k][8-padded])
    const float v0 = x[tid];
    float v1 = 0.f;
    if (tid < 256) v1 = x[512 + tid];
    xl[0][(tid & 127) * 8 + (tid >> 7)] = v0;
    if (tid < 256) { const int i = 512 + tid; xl[0][(i & 127) * 8 + (i >> 7)] = v1; }
  }
  __syncthreads();

  for (int t = 0; t < TT; ++t) {
    const float* xn = x + (size_t)((t + 1 < TT) ? t + 1 : TT - 1) * 768;
    const float v0p = xn[tid];
    float v1p = 0.f;
    if (tid < 256) v1p = xn[512 + tid];
    f2 acc[3] = {{0, 0}, {0, 0}, {0, 0}};
    {  // x-part (overlaps the poll)
      const float* xb = xl[t & 1] + (size_t)(w * 16) * 8;
#pragma unroll
      for (int kk = 0; kk < 16; ++kk) fma6(xb + kk * 8, wx[kk], acc);
    }
    {  // poll h1[t-1], unit tid (wave-self k-slice)
      float hv[6];
      poll6(h1L + (size_t)((t + 7) & 7) * 4096 + tid * 8,
            h1S + (size_t)((t + 7) & 7) * 4096 + tid * 8,
            (uint)((t - 1) >> 3) & TAGM, hv, mode);
      float* hp = hl + tid * 8;
      *(float4*)hp = make_float4(hv[0], hv[1], hv[2], hv[3]);
      *(float2*)(hp + 4) = make_float2(hv[4], hv[5]);
    }
    lds_wave_fence();  // wave w wrote hl[64w..64w+64) == slice it reads
    {
      const float* hb = hl + (size_t)(w * 64) * 8;
#pragma unroll
      for (int kk = 0; kk < 64; ++kk) fma6(hb + kk * 8, wh[kk], acc);
    }
    {
      float* zr = zred[t & 1] + w * 520 + c * 8;
      *(float4*)zr = make_float4(acc[0][0], acc[0][1], acc[1][0], acc[1][1]);
      *(float2*)(zr + 4) = make_float2(acc[2][0], acc[2][1]);
    }
    {  // stage x[t+1]
      float* xs = xl[(t + 1) & 1];
      xs[(tid & 127) * 8 + (tid >> 7)] = v0p;
      if (tid < 256) { const int i = 512 + tid; xs[(i & 127) * 8 + (i >> 7)] = v1p; }
    }
    __syncthreads();  // the only barrier per step
    if (tid < 96) {
      __builtin_amdgcn_s_setprio(1);
      const float* zb = zred[t & 1];
      float z[4];
#pragma unroll
      for (int g = 0; g < 4; ++g) {
        const int cc = g * 16 + gj;
        float s = 0.f;
#pragma unroll
        for (int p = 0; p < 8; ++p) s += zb[p * 520 + cc * 8 + gb];
        z[g] = s + bs[cc];
      }
      creg = sigm(z[1]) * creg + sigm(z[0]) * ftanh(z[2]);
      const float hval = sigm(z[3]) * ftanh(creg);
      const int gu = u0 + gj;
      const uint tg = (uint)(t >> 3) & TAGM;
      post_dual(h1L + (size_t)(t & 7) * 4096 + gu * 8 + gb,
                h1S + (size_t)(t & 7) * 4096 + gu * 8 + gb, hval, tg);
      __builtin_nontemporal_store(hval, seq1 + (size_t)t * 4096 + gu * 8 + gb);
      if (t == TT - 1) {
        post_dual(h2L + (size_t)7 * 4096 + gu * 8 + gb,
                  h2S + (size_t)7 * 4096 + gu * 8 + gb, hval, TAGM);  // L2 h-init
        c1fin[gu * 6 + gb] = creg;  // kernel-boundary flush covers it
      }
      __builtin_amdgcn_s_setprio(0);
    }
  }
}

// ===== K2: 32 workers; each owns 16 L2-units AND 4 L3-units (L3 skew -1) ====
__global__ __launch_bounds__(512, 2) void k_l23(
    const float* __restrict__ seq1, const float* __restrict__ Wi2,
    const float* __restrict__ Wh2, const float* __restrict__ b2,
    const float* __restrict__ Wi3, const float* __restrict__ Wh3,
    const float* __restrict__ b3, const float* __restrict__ c1fin,
    float* h2L, float* h2S, float* h3L, float* h3S, float* h3fin) {
  if (blockIdx.x & 7) return;
  const int slot = blockIdx.x >> 3;  // 0..31
  __shared__ float xls[2][512 * 8];
  __shared__ float hl[512 * 8];
  __shared__ float hl3[128 * 8];
  __shared__ float zred2[2][8 * 520];
  __shared__ float zred3[32 * 100];
  __shared__ float bs2[64];
  __shared__ float bs3[16];
  const int tid = threadIdx.x;
  const int c = tid & 63, w = tid >> 6;
  const int gj = tid / 6, gb = tid % 6;
  // L2 mapping: 64 cols (4 gates x 16 units), 8 k-slices of 64
  const int u0 = slot * 16;
  const int gcol = ((c >> 4) * 512) + u0 + (c & 15);
  float wh[64], wx[64];
#pragma unroll
  for (int kk = 0; kk < 64; ++kk) {
    wh[kk] = Wh2[(size_t)(w * 64 + kk) * 2048 + gcol];
    wx[kk] = Wi2[(size_t)(w * 64 + kk) * 2048 + gcol];
  }
  // L3 mapping: 16 cols (4 gates x 4 units), 32 k-slices of 20 over K=640
  const int c3 = tid & 15, ks3 = tid >> 4;
  const int v0 = slot * 4;
  const int gcol3 = ((c3 >> 2) * 128) + v0 + (c3 & 3);
  float w3[20];
#pragma unroll
  for (int kk = 0; kk < 20; ++kk) {
    const int k = ks3 * 20 + kk;
    w3[kk] = (k < 512) ? Wi3[(size_t)k * 512 + gcol3]
                       : Wh3[(size_t)(k - 512) * 512 + gcol3];
  }
  if (tid < 64) bs2[tid] = b2[((tid >> 4) * 512) + u0 + (tid & 15)];
  if (tid < 16) bs3[tid] = b3[((tid >> 2) * 128) + v0 + (tid & 3)];
  float creg = (tid < 96) ? c1fin[(u0 + gj) * 6 + gb] : 0.f;
  float creg3 = 0.f;
  int mode2 = 0, mode3 = 0;
  {  // stage seq1[0] (row tid; wave-self slice)
    const float4 s0 = *(const float4*)(seq1 + (size_t)tid * 8);
    const float2 s1 = *(const float2*)(seq1 + (size_t)tid * 8 + 4);
    float* xs = xls[0] + tid * 8;
    *(float4*)xs = s0;
    *(float2*)(xs + 4) = s1;
  }
  __syncthreads();

  for (int t = 0; t <= TT; ++t) {
    float4 p0; float2 p1;
    f2 acc[3] = {{0, 0}, {0, 0}, {0, 0}};
    if (t < TT) {
      const int tn = (t + 1 < TT) ? t + 1 : TT - 1;  // prefetch seq1[t+1]
      p0 = *(const float4*)(seq1 + (size_t)tn * 4096 + (size_t)tid * 8);
      p1 = *(const float2*)(seq1 + (size_t)tn * 4096 + (size_t)tid * 8 + 4);
      const float* xb = xls[t & 1] + (size_t)(w * 64) * 8;  // x-part pre-wait
#pragma unroll
      for (int kk = 0; kk < 64; ++kk) fma6(xb + kk * 8, wx[kk], acc);
    }
    if (t >= 1 && tid < 128) {  // poll h3[t-2] (128 units; usually 1 shot)
      const int s3 = t - 2;
      float hv[6];
      poll6(h3L + (size_t)((t + 6) & 7) * 1024 + tid * 8,
            h3S + (size_t)((t + 6) & 7) * 1024 + tid * 8,
            (uint)(s3 >> 3) & TAGM, hv, mode3);
      float* hp = hl3 + tid * 8;
      *(float4*)hp = make_float4(hv[0], hv[1], hv[2], hv[3]);
      *(float2*)(hp + 4) = make_float2(hv[4], hv[5]);
    }
    {  // poll h2[t-1], unit tid
      float hv[6];
      poll6(h2L + (size_t)((t + 7) & 7) * 4096 + tid * 8,
            h2S + (size_t)((t + 7) & 7) * 4096 + tid * 8,
            (uint)((t - 1) >> 3) & TAGM, hv, mode2);
      float* hp = hl + tid * 8;
      *(float4*)hp = make_float4(hv[0], hv[1], hv[2], hv[3]);
      *(float2*)(hp + 4) = make_float2(hv[4], hv[5]);
    }
    lds_wave_fence();
    if (t < TT) {
      const float* hb = hl + (size_t)(w * 64) * 8;  // wave-self slice
#pragma unroll
      for (int kk = 0; kk < 64; ++kk) fma6(hb + kk * 8, wh[kk], acc);
      float* zr = zred2[t & 1] + w * 520 + c * 8;
      *(float4*)zr = make_float4(acc[0][0], acc[0][1], acc[1][0], acc[1][1]);
      *(float2*)(zr + 4) = make_float2(acc[2][0], acc[2][1]);
      float* xs = xls[(t + 1) & 1] + tid * 8;  // stage seq1[t+1]
      *(float4*)xs = p0;
      *(float2*)(xs + 4) = p1;
    }
    __syncthreads();  // B
    if (t < TT && tid < 96) {  // L2 gates + post h2[t]
      __builtin_amdgcn_s_setprio(1);
      const float* zb = zred2[t & 1];
      float z[4];
#pragma unroll
      for (int g = 0; g < 4; ++g) {
        const int cc = g * 16 + gj;
        float s = 0.f;
#pragma unroll
        for (int p = 0; p < 8; ++p) s += zb[p * 520 + cc * 8 + gb];
        z[g] = s + bs2[cc];
      }
      creg = sigm(z[1]) * creg + sigm(z[0]) * ftanh(z[2]);
      const float hval = sigm(z[3]) * ftanh(creg);
      const uint tg = (uint)(t >> 3) & TAGM;
      post_dual(h2L + (size_t)(t & 7) * 4096 + (u0 + gj) * 8 + gb,
                h2S + (size_t)(t & 7) * 4096 + (u0 + gj) * 8 + gb, hval, tg);
      __builtin_amdgcn_s_setprio(0);
    }
    if (t >= 1) {  // L3 FMA for step s=t-1 (hl = h2[t-1], hl3 = h3[t-2])
      f2 a3[3] = {{0, 0}, {0, 0}, {0, 0}};
#pragma unroll
      for (int kk = 0; kk < 20; ++kk) {
        const int k = ks3 * 20 + kk;
        const float* vp = (k < 512) ? (hl + k * 8) : (hl3 + (k - 512) * 8);
        fma6(vp, w3[kk], a3);
      }
      float* zr = zred3 + ks3 * 100 + c3 * 6;
      *(float2*)(zr) = make_float2(a3[0][0], a3[0][1]);
      *(float2*)(zr + 2) = make_float2(a3[1][0], a3[1][1]);
      *(float2*)(zr + 4) = make_float2(a3[2][0], a3[2][1]);
    }
    __syncthreads();  // C
    if (t >= 1 && tid < 24) {  // L3 gates: direct 32-row sums (wave 0 only)
      __builtin_amdgcn_s_setprio(1);
      const int s = t - 1;
      const int j3 = tid / 6;  // unit 0..3
      float z3[4];
#pragma unroll
      for (int g = 0; g < 4; ++g) {
        const int cc3 = g * 4 + j3;
        float sum = 0.f;
#pragma unroll
        for (int r = 0; r < 32; ++r) sum += zred3[r * 100 + cc3 * 6 + gb];
        z3[g] = sum + bs3[cc3];
      }
      creg3 = sigm(z3[1]) * creg3 + sigm(z3[0]) * ftanh(z3[2]);
      const float hv3 = sigm(z3[3]) * ftanh(creg3);
      const uint tg3 = (uint)(s >> 3) & TAGM;
      post_dual(h3L + (size_t)(s & 7) * 1024 + (v0 + j3) * 8 + gb,
                h3S + (size_t)(s & 7) * 1024 + (v0 + j3) * 8 + gb, hv3, tg3);
      if (s == TT - 1) h3fin[(v0 + j3) * 6 + gb] = hv3;
      __builtin_amdgcn_s_setprio(0);
    }
  }
}

// ================= K3: out[b] = h3fin[:,b] @ Wl + bl ========================
__global__ void k_out(const float* __restrict__ h3fin, const float* __restrict__ Wl,
                      const float* __restrict__ bl, float* __restrict__ out) {
  const int tid = threadIdx.x;  // 64
  float p[6] = {0, 0, 0, 0, 0, 0};
  for (int k = tid; k < 128; k += 64) {
    const float w = Wl[k];
#pragma unroll
    for (int b = 0; b < 6; ++b) p[b] += h3fin[k * 6 + b] * w;
  }
#pragma unroll
  for (int off = 32; off > 0; off >>= 1) {
#pragma unroll
    for (int b = 0; b < 6; ++b) p[b] += __shfl_down(p[b], off);
  }
  if (tid == 0) {
#pragma unroll
    for (int b = 0; b < 6; ++b) out[b] = p[b] + bl[0];
  }
}

// ================= host launcher ============================================
extern "C" void kernel_launch(void* const* d_in, const int* in_sizes, int n_in,
                              void* d_out, int out_size, void* d_ws, size_t ws_size,
                              hipStream_t stream) {
  (void)in_sizes; (void)n_in; (void)out_size;
  const float* x   = (const float*)d_in[0];
  const float* Wi1 = (const float*)d_in[1];
  const float* Wh1 = (const float*)d_in[2];
  const float* b1  = (const float*)d_in[3];
  const float* Wi2 = (const float*)d_in[4];
  const float* Wh2 = (const float*)d_in[5];
  const float* b2  = (const float*)d_in[6];
  const float* Wi3 = (const float*)d_in[7];
  const float* Wh3 = (const float*)d_in[8];
  const float* b3  = (const float*)d_in[9];
  const float* Wl  = (const float*)d_in[10];
  const float* bl  = (const float*)d_in[11];

  // ws layout (bytes). Rings: 8 slots x 512(128) units x 8 floats.
  //   [0)       h1L  131072          [131072)  h1S  131072
  //   [262144)  h2L  131072          [393216)  h2S  131072
  //   [524288)  h3L   32768          [557056)  h3S   32768
  //   [589824)  c1fin 12288          [602112)  h3fin  3072
  //   [606208)  seq1  4096*512*8 f = 67108864  (padded [t][512][8])
  char* wsb = (char*)d_ws;
  float* h1L = (float*)(wsb + 0);
  float* h1S = (float*)(wsb + 131072);
  float* h2L = (float*)(wsb + 262144);
  float* h2S = (float*)(wsb + 393216);
  float* h3L = (float*)(wsb + 524288);
  float* h3S = (float*)(wsb + 557056);
  float* c1fin = (float*)(wsb + 589824);
  float* h3fin = (float*)(wsb + 602112);
  float* seq1  = (float*)(wsb + 606208);

  const size_t need = 606208 + (size_t)TT * 512 * 8 * sizeof(float);
  if (ws_size < need) {
    hipMemsetAsync(d_out, 0, 6 * sizeof(float), stream);
    return;
  }

  // reset control region; seed t=-1 slots (slot 7) with tag 31 (byte 0x1F:
  // low-5 bits = 31, value after tag-strip ~3e-20 ~= 0). Seed BOTH rings.
  hipMemsetAsync(d_ws, 0, 606208, stream);
  hipMemsetAsync(wsb + 0      + 7 * 16384, 0x1F, 16384, stream);  // h1L slot7
  hipMemsetAsync(wsb + 131072 + 7 * 16384, 0x1F, 16384, stream);  // h1S slot7
  hipMemsetAsync(wsb + 524288 + 7 * 4096,  0x1F, 4096,  stream);  // h3L slot7
  hipMemsetAsync(wsb + 557056 + 7 * 4096,  0x1F, 4096,  stream);  // h3S slot7

  k_l1 <<<256, 512, 0, stream>>>(x, Wi1, Wh1, b1, h1L, h1S, h2L, h2S, c1fin, seq1);
  k_l23<<<256, 512, 0, stream>>>(seq1, Wi2, Wh2, b2, Wi3, Wh3, b3, c1fin,
                                 h2L, h2S, h3L, h3S, h3fin);
  k_out<<<1, 64, 0, stream>>>(h3fin, Wl, bl, (float*)d_out);
}

// Round 8
// 90463.110 us; speedup vs baseline: 2.0515x; 2.0515x over previous
//
#include <hip/hip_runtime.h>

#define TT 4096
typedef unsigned int uint;
typedef unsigned long long u64;

#define TAGM 31u  // 5-bit wrap tag in mantissa LSBs (rel err 2^-19)

static __device__ __forceinline__ float sigm(float x) { return 1.f / (1.f + __expf(-x)); }
static __device__ __forceinline__ float ftanh(float x) {
  x = fminf(fmaxf(x, -15.f), 15.f);
  const float e = __expf(-2.f * x);
  return (1.f - e) / (1.f + e);
}
static __device__ __forceinline__ void lds_wave_fence() {
  asm volatile("s_waitcnt lgkmcnt(0)" ::: "memory");
  __builtin_amdgcn_sched_barrier(0);
}
static __device__ __forceinline__ uint tagw(float v, uint tg) {
  return (__float_as_uint(v) & ~TAGM) | tg;
}
// tag for h[t]; t=-1/-2 -> 0 == zero-initialized ring (h[-1]=0 is valid data).
static __device__ __forceinline__ uint tg_of(int t) {
  return (t < 0) ? 0u : (uint)(((t >> 3) + 1) & 31);
}
static __device__ __forceinline__ void posta(float* p, float v, uint tg) {
  __hip_atomic_store((uint*)p, tagw(v, tg), __ATOMIC_RELAXED, __HIP_MEMORY_SCOPE_AGENT);
}
static __device__ __forceinline__ void lda3(const float* p, u64& a0, u64& a1, u64& a2) {
  const u64* q = (const u64*)p;
  a0 = __hip_atomic_load(q + 0, __ATOMIC_RELAXED, __HIP_MEMORY_SCOPE_AGENT);
  a1 = __hip_atomic_load(q + 1, __ATOMIC_RELAXED, __HIP_MEMORY_SCOPE_AGENT);
  a2 = __hip_atomic_load(q + 2, __ATOMIC_RELAXED, __HIP_MEMORY_SCOPE_AGENT);
}
static __device__ __forceinline__ bool tag6(u64 a0, u64 a1, u64 a2, uint tg) {
  const uint m = ((uint)a0 ^ tg) | ((uint)(a0 >> 32) ^ tg) | ((uint)a1 ^ tg) |
                 ((uint)(a1 >> 32) ^ tg) | ((uint)a2 ^ tg) | ((uint)(a2 >> 32) ^ tg);
  return (m & TAGM) == 0u;
}
static __device__ __forceinline__ void unpack6(u64 a0, u64 a1, u64 a2, float* hp) {
  hp[0] = __uint_as_float((uint)a0 & ~TAGM);
  hp[1] = __uint_as_float((uint)(a0 >> 32) & ~TAGM);
  hp[2] = __uint_as_float((uint)a1 & ~TAGM);
  hp[3] = __uint_as_float((uint)(a1 >> 32) & ~TAGM);
  hp[4] = __uint_as_float((uint)a2 & ~TAGM);
  hp[5] = __uint_as_float((uint)(a2 >> 32) & ~TAGM);
}
// acc[b] += v[b] * w over the 6 batches; v is a 32B-aligned stride-8 row.
static __device__ __forceinline__ void fma6(const float* vp, float w, float acc[6]) {
  const float4 v0 = *(const float4*)vp;
  const float2 v1 = *(const float2*)(vp + 4);
  acc[0] += v0.x * w; acc[1] += v0.y * w; acc[2] += v0.z * w;
  acc[3] += v0.w * w; acc[4] += v1.x * w; acc[5] += v1.y * w;
}

// ================= K1: LSTM layer 1 — 32 WGs x 512 thr, 16 units/WG =========
// Self-contained pool: only these 32 WGs touch h1ring. One barrier per step.
__global__ __launch_bounds__(512, 2) void k_l1(
    const float* __restrict__ x, const float* __restrict__ Wi,
    const float* __restrict__ Wh, const float* __restrict__ bias,
    float* h1ring, float* h2ring, float* c1fin, float* seq1) {
  __shared__ float xl[2][128 * 8];
  __shared__ float hl[512 * 8];
  __shared__ float zred[2][8 * 520];
  __shared__ float bs[64];
  const int tid = threadIdx.x, slot = blockIdx.x;
  const int c = tid & 63, w = tid >> 6;
  const int u0 = slot * 16;
  const int gcol = ((c >> 4) * 512) + u0 + (c & 15);
  float wh[64], wx[16];
#pragma unroll
  for (int kk = 0; kk < 64; ++kk) wh[kk] = Wh[(size_t)(w * 64 + kk) * 2048 + gcol];
#pragma unroll
  for (int kk = 0; kk < 16; ++kk) wx[kk] = Wi[(size_t)(w * 16 + kk) * 2048 + gcol];
  if (tid < 64) bs[tid] = bias[((tid >> 4) * 512) + u0 + (tid & 15)];
  const int gj = tid / 6, gb = tid % 6;  // gate lanes: tid<96
  float creg = 0.f;
  {  // stage x[0] (transpose [b][k] -> [k][8-pad])
    const float v0 = x[tid];
    float v1 = 0.f;
    if (tid < 256) v1 = x[512 + tid];
    xl[0][(tid & 127) * 8 + (tid >> 7)] = v0;
    if (tid < 256) { const int i = 512 + tid; xl[0][(i & 127) * 8 + (i >> 7)] = v1; }
  }
  __syncthreads();

  for (int t = 0; t < TT; ++t) {
    // issue poll first-shot, then overlap with prefetch + x-part
    const float* prow = h1ring + (size_t)((t + 7) & 7) * 4096 + tid * 8;
    u64 a0, a1, a2;
    lda3(prow, a0, a1, a2);
    const uint tgp = tg_of(t - 1);
    const float* xn = x + (size_t)((t + 1 < TT) ? t + 1 : TT - 1) * 768;
    const float v0p = xn[tid];
    float v1p = 0.f;
    if (tid < 256) v1p = xn[512 + tid];
    float acc[6] = {0, 0, 0, 0, 0, 0};
    {
      const float* xb = xl[t & 1] + (size_t)(w * 16) * 8;
#pragma unroll
      for (int kk = 0; kk < 16; ++kk) fma6(xb + kk * 8, wx[kk], acc);
    }
    while (!tag6(a0, a1, a2, tgp)) { __builtin_amdgcn_s_sleep(1); lda3(prow, a0, a1, a2); }
    unpack6(a0, a1, a2, hl + tid * 8);
    lds_wave_fence();  // wave w wrote hl rows [64w,64w+64) == slice it reads
    {
      const float* hb = hl + (size_t)(w * 64) * 8;
#pragma unroll
      for (int kk = 0; kk < 64; ++kk) fma6(hb + kk * 8, wh[kk], acc);
    }
    {
      float* zr = zred[t & 1] + w * 520 + c * 8;
      *(float4*)zr = make_float4(acc[0], acc[1], acc[2], acc[3]);
      *(float2*)(zr + 4) = make_float2(acc[4], acc[5]);
    }
    {  // stage x[t+1]
      float* xs = xl[(t + 1) & 1];
      xs[(tid & 127) * 8 + (tid >> 7)] = v0p;
      if (tid < 256) { const int i = 512 + tid; xs[(i & 127) * 8 + (i >> 7)] = v1p; }
    }
    __syncthreads();  // the only barrier per step
    if (tid < 96) {
      __builtin_amdgcn_s_setprio(1);
      const float* zb = zred[t & 1];
      float z[4];
#pragma unroll
      for (int g = 0; g < 4; ++g) {
        const int cc = g * 16 + gj;
        float s = 0.f;
#pragma unroll
        for (int p = 0; p < 8; ++p) s += zb[p * 520 + cc * 8 + gb];
        z[g] = s + bs[cc];
      }
      creg = sigm(z[1]) * creg + sigm(z[0]) * ftanh(z[2]);
      const float hval = sigm(z[3]) * ftanh(creg);
      const int gu = u0 + gj;
      posta(h1ring + (size_t)(t & 7) * 4096 + gu * 8 + gb, hval, tg_of(t));
      __builtin_nontemporal_store(hval, seq1 + (size_t)t * 4096 + gu * 8 + gb);
      if (t == TT - 1) {  // serial handoff: plain stores, kernel-boundary flush
        *(uint*)(h2ring + (size_t)7 * 4096 + gu * 8 + gb) = tagw(hval, 0u);
        c1fin[gu * 6 + gb] = creg;
      }
      __builtin_amdgcn_s_setprio(0);
    }
  }
}

// ===== K2: runs AFTER k_l1 (stream order). 32 WGs; 16 L2-units + 4 L3-units
// each, L3 skewed one step behind L2. Two barriers per step. ==================
__global__ __launch_bounds__(512, 2) void k_l23(
    const float* __restrict__ seq1, const float* __restrict__ Wi2,
    const float* __restrict__ Wh2, const float* __restrict__ b2,
    const float* __restrict__ Wi3, const float* __restrict__ Wh3,
    const float* __restrict__ b3, const float* __restrict__ c1fin,
    float* h2ring, float* h3ring, float* h3fin) {
  __shared__ float xls[2][512 * 8];
  __shared__ float hl[512 * 8];
  __shared__ float hl3[128 * 8];
  __shared__ float zred2[2][8 * 520];
  __shared__ float zred3[32 * 100];
  __shared__ float bs2[64];
  __shared__ float bs3[16];
  const int tid = threadIdx.x, slot = blockIdx.x;
  const int c = tid & 63, w = tid >> 6;
  const int gj = tid / 6, gb = tid % 6;
  const int u0 = slot * 16;
  const int gcol = ((c >> 4) * 512) + u0 + (c & 15);
  float wh[64], wx[64];
#pragma unroll
  for (int kk = 0; kk < 64; ++kk) {
    wh[kk] = Wh2[(size_t)(w * 64 + kk) * 2048 + gcol];
    wx[kk] = Wi2[(size_t)(w * 64 + kk) * 2048 + gcol];
  }
  // L3: 16 cols (4 gates x 4 units), 32 k-slices of 20 over K=640 ([h2;h3])
  const int c3 = tid & 15, ks3 = tid >> 4;
  const int v0 = slot * 4;
  const int gcol3 = ((c3 >> 2) * 128) + v0 + (c3 & 3);
  float w3[20];
#pragma unroll
  for (int kk = 0; kk < 20; ++kk) {
    const int k = ks3 * 20 + kk;
    w3[kk] = (k < 512) ? Wi3[(size_t)k * 512 + gcol3]
                       : Wh3[(size_t)(k - 512) * 512 + gcol3];
  }
  if (tid < 64) bs2[tid] = b2[((tid >> 4) * 512) + u0 + (tid & 15)];
  if (tid < 16) bs3[tid] = b3[((tid >> 2) * 128) + v0 + (tid & 3)];
  float creg = (tid < 96) ? c1fin[(u0 + gj) * 6 + gb] : 0.f;
  float creg3 = 0.f;
  {  // stage seq1[0]
    const float4 s0 = *(const float4*)(seq1 + (size_t)tid * 8);
    const float2 s1 = *(const float2*)(seq1 + (size_t)tid * 8 + 4);
    float* xs = xls[0] + tid * 8;
    *(float4*)xs = s0;
    *(float2*)(xs + 4) = s1;
  }
  __syncthreads();

  for (int t = 0; t <= TT; ++t) {
    // issue poll first-shots
    const float* p2 = h2ring + (size_t)((t + 7) & 7) * 4096 + tid * 8;
    u64 a0, a1, a2;
    lda3(p2, a0, a1, a2);
    const uint tg2 = tg_of(t - 1);
    u64 d0 = 0, d1 = 0, d2 = 0;
    const float* p3 = h3ring + (size_t)((t + 6) & 7) * 1024 + tid * 8;
    const uint tg3 = tg_of(t - 2);
    const bool do3 = (t >= 1) && (tid < 128);
    if (do3) lda3(p3, d0, d1, d2);
    // prefetch + x-part overlap the poll latency
    float4 q0 = make_float4(0, 0, 0, 0);
    float2 q1 = make_float2(0, 0);
    float acc[6] = {0, 0, 0, 0, 0, 0};
    if (t < TT) {
      const int tn = (t + 1 < TT) ? t + 1 : TT - 1;
      q0 = *(const float4*)(seq1 + (size_t)tn * 4096 + (size_t)tid * 8);
      q1 = *(const float2*)(seq1 + (size_t)tn * 4096 + (size_t)tid * 8 + 4);
      const float* xb = xls[t & 1] + (size_t)(w * 64) * 8;
#pragma unroll
      for (int kk = 0; kk < 64; ++kk) fma6(xb + kk * 8, wx[kk], acc);
    }
    if (do3) {
      while (!tag6(d0, d1, d2, tg3)) { __builtin_amdgcn_s_sleep(1); lda3(p3, d0, d1, d2); }
      unpack6(d0, d1, d2, hl3 + tid * 8);
    }
    while (!tag6(a0, a1, a2, tg2)) { __builtin_amdgcn_s_sleep(1); lda3(p2, a0, a1, a2); }
    unpack6(a0, a1, a2, hl + tid * 8);
    lds_wave_fence();  // own-wave hl slice below; hl3 is read only after B
    if (t < TT) {
      const float* hb = hl + (size_t)(w * 64) * 8;
#pragma unroll
      for (int kk = 0; kk < 64; ++kk) fma6(hb + kk * 8, wh[kk], acc);
      float* zr = zred2[t & 1] + w * 520 + c * 8;
      *(float4*)zr = make_float4(acc[0], acc[1], acc[2], acc[3]);
      *(float2*)(zr + 4) = make_float2(acc[4], acc[5]);
      float* xs = xls[(t + 1) & 1] + tid * 8;  // stage seq1[t+1]
      *(float4*)xs = q0;
      *(float2*)(xs + 4) = q1;
    }
    __syncthreads();  // B
    if (t < TT && tid < 96) {  // L2 gates + post h2[t]
      __builtin_amdgcn_s_setprio(1);
      const float* zb = zred2[t & 1];
      float z[4];
#pragma unroll
      for (int g = 0; g < 4; ++g) {
        const int cc = g * 16 + gj;
        float s = 0.f;
#pragma unroll
        for (int p = 0; p < 8; ++p) s += zb[p * 520 + cc * 8 + gb];
        z[g] = s + bs2[cc];
      }
      creg = sigm(z[1]) * creg + sigm(z[0]) * ftanh(z[2]);
      const float hval = sigm(z[3]) * ftanh(creg);
      posta(h2ring + (size_t)(t & 7) * 4096 + (u0 + gj) * 8 + gb, hval, tg_of(t));
      __builtin_amdgcn_s_setprio(0);
    }
    if (t >= 1) {  // L3 FMA for step s=t-1 (hl=h2[t-1], hl3=h3[t-2])
      float a3[6] = {0, 0, 0, 0, 0, 0};
#pragma unroll
      for (int kk = 0; kk < 20; ++kk) {
        const int k = ks3 * 20 + kk;
        const float* vp = (k < 512) ? (hl + (size_t)k * 8) : (hl3 + (size_t)(k - 512) * 8);
        fma6(vp, w3[kk], a3);
      }
      float* zr = zred3 + ks3 * 100 + c3 * 6;
      *(float2*)(zr) = make_float2(a3[0], a3[1]);
      *(float2*)(zr + 2) = make_float2(a3[2], a3[3]);
      *(float2*)(zr + 4) = make_float2(a3[4], a3[5]);
    }
    __syncthreads();  // C
    if (t >= 1 && tid < 24) {  // L3 gates + post h3[t-1]
      __builtin_amdgcn_s_setprio(1);
      const int s = t - 1;
      const int j3 = tid / 6;
      float z3[4];
#pragma unroll
      for (int g = 0; g < 4; ++g) {
        const int cc3 = g * 4 + j3;
        float sum = 0.f;
#pragma unroll
        for (int r = 0; r < 32; ++r) sum += zred3[r * 100 + cc3 * 6 + gb];
        z3[g] = sum + bs3[cc3];
      }
      creg3 = sigm(z3[1]) * creg3 + sigm(z3[0]) * ftanh(z3[2]);
      const float hv3 = sigm(z3[3]) * ftanh(creg3);
      posta(h3ring + (size_t)(s & 7) * 1024 + (v0 + j3) * 8 + gb, hv3, tg_of(s));
      if (s == TT - 1) h3fin[(v0 + j3) * 6 + gb] = hv3;
      __builtin_amdgcn_s_setprio(0);
    }
  }
}

// ================= K3: out[b] = h3fin[:,b] @ Wl + bl ========================
__global__ void k_out(const float* __restrict__ h3fin, const float* __restrict__ Wl,
                      const float* __restrict__ bl, float* __restrict__ out) {
  const int tid = threadIdx.x;  // 64
  float p[6] = {0, 0, 0, 0, 0, 0};
  for (int k = tid; k < 128; k += 64) {
    const float w = Wl[k];
#pragma unroll
    for (int b = 0; b < 6; ++b) p[b] += h3fin[k * 6 + b] * w;
  }
#pragma unroll
  for (int off = 32; off > 0; off >>= 1) {
#pragma unroll
    for (int b = 0; b < 6; ++b) p[b] += __shfl_down(p[b], off);
  }
  if (tid == 0) {
#pragma unroll
    for (int b = 0; b < 6; ++b) out[b] = p[b] + bl[0];
  }
}

// ================= host launcher ============================================
extern "C" void kernel_launch(void* const* d_in, const int* in_sizes, int n_in,
                              void* d_out, int out_size, void* d_ws, size_t ws_size,
                              hipStream_t stream) {
  (void)in_sizes; (void)n_in; (void)out_size;
  const float* x   = (const float*)d_in[0];
  const float* Wi1 = (const float*)d_in[1];
  const float* Wh1 = (const float*)d_in[2];
  const float* b1  = (const float*)d_in[3];
  const float* Wi2 = (const float*)d_in[4];
  const float* Wh2 = (const float*)d_in[5];
  const float* b2  = (const float*)d_in[6];
  const float* Wi3 = (const float*)d_in[7];
  const float* Wh3 = (const float*)d_in[8];
  const float* b3  = (const float*)d_in[9];
  const float* Wl  = (const float*)d_in[10];
  const float* bl  = (const float*)d_in[11];

  // ws layout (bytes). Rings: 8 slots x units x 8 floats (32B rows).
  //   [0)       h1ring 131072
  //   [131072)  h2ring 131072
  //   [262144)  h3ring  32768
  //   [294912)  c1fin   12288
  //   [307200)  h3fin    3072
  //   [327680)  seq1   4096*512*8 f = 67108864  (padded [t][512][8])
  char* wsb = (char*)d_ws;
  float* h1ring = (float*)(wsb + 0);
  float* h2ring = (float*)(wsb + 131072);
  float* h3ring = (float*)(wsb + 262144);
  float* c1fin  = (float*)(wsb + 294912);
  float* h3fin  = (float*)(wsb + 307200);
  float* seq1   = (float*)(wsb + 327680);

  const size_t need = 327680 + (size_t)TT * 512 * 8 * sizeof(float);
  if (ws_size < need) {
    hipMemsetAsync(d_out, 0, 6 * sizeof(float), stream);
    return;
  }

  // zero rings/state every call. Zeroed ring == valid h[-1]=0 under tg_of
  // (tag(t<0)=0, tag(t>=0)>=1 for the first wrap) — no seeding needed.
  hipMemsetAsync(d_ws, 0, 327680, stream);

  // Phases are inherently serial (L2 init = L1 final state): stream order
  // provides the dependency; no cross-kernel polling exists.
  k_l1 <<<32, 512, 0, stream>>>(x, Wi1, Wh1, b1, h1ring, h2ring, c1fin, seq1);
  k_l23<<<32, 512, 0, stream>>>(seq1, Wi2, Wh2, b2, Wi3, Wh3, b3, c1fin,
                                h2ring, h3ring, h3fin);
  k_out<<<1, 64, 0, stream>>>(h3fin, Wl, bl, (float*)d_out);
}